// Round 6
// baseline (215.390 us; speedup 1.0000x reference)
//
#include <hip/hip_runtime.h>
#include <stdint.h>

// out[m,n] = prod_d softplus(min(Zm,Ze)-max(zm,ze)) / softplus(Zm-zm)
//
// R6 = R5 design with the fp16 API fixed: ROCm 7.2 hip_fp16.h lacks
// __hmin2/__hmax2, so we use clang-native _Float16 ext-vectors +
// __builtin_elementwise_min/max (lower to v_pk_min/max/add_f16 directly).
//
//  1) ivr_stats (1 block): per-m constants. Lm = sum_d log2(softplus(Zm-zm)),
//     rcM[m][c] = 1/prod_{8d} log2(1+e^s), Cm[m] = survivor threshold on T:
//       Jensen (concave log2 softplus): log2(out) <= 64*log2(sp(T/64)) - Lm
//       (bound >= -43.5) <=> (T >= Cm),  Cm = 64*ln(expm1(exp2((Lm-43.5)/64)))
//  2) ivr_bound (dense): T = sum_d t_d in packed fp16, f32 collapse per 8-d
//     chunk; writes 0 everywhere; ballot-compacts survivors into ws queue.
//     Safety: zeroed => true < 2^(-43.5+1.7) < 2.7e-13 < thr(8.09e-13);
//     true >= thr => T clears Cm by >= 2.3 log2 >> fp16 err (<=~1.2).
//  3) ivr_exact: grid-stride over compacted queue, R2-accurate math.
//  Fallback: self-contained R2 kernel.

#define BM 32
#define BN 64
#define CUT 43.5f
#define QOFF 9232   // bytes: 16 (count) + 1024 (Cm) + 8192 (rcM)

typedef _Float16 h2 __attribute__((ext_vector_type(2)));
typedef _Float16 h4 __attribute__((ext_vector_type(4)));

// ---------------- kernel 1: per-m constants ----------------
__global__ __launch_bounds__(256)
void ivr_stats(const float* __restrict__ men, float* __restrict__ ws, int M) {
    const int tx = threadIdx.x;
    if (tx == 0) *((unsigned*)ws) = 0u;
    float* Cm  = (float*)((char*)ws + 16);
    float* rcM = Cm + 256;
    if (tx >= M) return;
    const float* row = men + (size_t)tx * 128;
    float Lm = 0.f;
    for (int c = 0; c < 8; ++c) {
        float prod = 1.f;
        #pragma unroll
        for (int k = 0; k < 8; ++k) {
            const int d = c * 8 + k;
            const float u = __expf(row[64 + d] - row[d]);
            const float w = 1.f + u;
            float l2 = __log2f(w);
            if (u < 0.5f) l2 += (u - (w - 1.f)) * 1.44269504f;  // log1p fixup
            prod *= l2;
            Lm += __log2f(l2 * 0.69314718f);   // log2(ln-softplus)
        }
        rcM[tx * 8 + c] = 1.f / prod;
    }
    const float V = exp2f((Lm - CUT) * (1.f / 64.f));
    Cm[tx] = 64.f * __logf(expm1f(V));
}

// ---------------- kernel 2: dense fp16 bound + compaction ----------------
__global__ __launch_bounds__(256, 4)
void ivr_bound(const float* __restrict__ men, const float* __restrict__ en,
               float* __restrict__ out, float* __restrict__ ws,
               int M, int N, unsigned qcap) {
    __shared__ _Float16 sEZ[64][68];   // Ze  [d][n]
    __shared__ _Float16 sEz[64][68];   // ze
    __shared__ _Float16 sMZ[64][68];   // Zm replicated x2: [d][2m],[d][2m+1]
    __shared__ _Float16 sMz[64][68];   // zm replicated x2

    const int tx = threadIdx.x;
    const int m0 = blockIdx.y * BM;
    const int n0 = blockIdx.x * BN;
    const float* Cm = (const float*)((const char*)ws + 16);
    unsigned* qcount = (unsigned*)ws;
    unsigned* queue  = (unsigned*)((char*)ws + QOFF);

    // ---- entity staging: thread -> (n-quad nq=tx&15, d-quad (tx>>4)*4) ----
    {
        const int nq = tx & 15;
        const int db = (tx >> 4) * 4;
        const float* er[4];
        #pragma unroll
        for (int k = 0; k < 4; ++k) {
            int nn = n0 + nq * 4 + k; if (nn >= N) nn = N - 1;
            er[k] = en + (size_t)nn * 128;
        }
        #pragma unroll
        for (int j = 0; j < 4; ++j) {
            const int d = db + j;
            h4 hz, hZ;
            #pragma unroll
            for (int k = 0; k < 4; ++k) {
                hz[k] = (_Float16)er[k][d];
                hZ[k] = (_Float16)er[k][64 + d];
            }
            *(h4*)&sEz[d][nq * 4] = hz;     // 8B store, 8B-aligned
            *(h4*)&sEZ[d][nq * 4] = hZ;
        }
    }
    // ---- men staging: thread -> (m=tx&31, 8 d's at (tx>>5)*8) ----
    {
        const int m = tx & 31;
        const int db8 = (tx >> 5) * 8;
        int mm = m0 + m; if (mm >= M) mm = M - 1;
        const float* row = men + (size_t)mm * 128;
        #pragma unroll
        for (int k = 0; k < 8; ++k) {
            const int d = db8 + k;
            const _Float16 vz = (_Float16)row[d];
            const _Float16 vZ = (_Float16)row[64 + d];
            *(h2*)&sMz[d][2 * m] = (h2){vz, vz};   // 4B store, 4B-aligned
            *(h2*)&sMZ[d][2 * m] = (h2){vZ, vZ};
        }
    }
    __syncthreads();

    const int tn = tx & 15, tm = tx >> 4;
    const int ni = tn * 4, mi = tm * 2;

    float acc[2][4];
    #pragma unroll
    for (int i = 0; i < 2; ++i)
        #pragma unroll
        for (int j = 0; j < 4; ++j) acc[i][j] = 0.f;

    #pragma unroll 1
    for (int c = 0; c < 8; ++c) {
        h2 ca[2][2];
        ca[0][0] = ca[0][1] = ca[1][0] = ca[1][1] = (h2)(_Float16)0;
        #pragma unroll
        for (int k = 0; k < 8; ++k) {
            const int d = c * 8 + k;
            const h4 eZ = *(const h4*)&sEZ[d][ni];      // Ze[ni..ni+3]
            const h4 ez = *(const h4*)&sEz[d][ni];
            const h4 mZ = *(const h4*)&sMZ[d][2 * mi];  // (m_mi x2, m_mi+1 x2)
            const h4 mz = *(const h4*)&sMz[d][2 * mi];
            #pragma unroll
            for (int i = 0; i < 2; ++i) {
                const h2 mZ2 = i ? mZ.zw : mZ.xy;       // replicated pair
                const h2 mz2 = i ? mz.zw : mz.xy;
                ca[i][0] = ca[i][0] +
                    (__builtin_elementwise_min(eZ.xy, mZ2) -
                     __builtin_elementwise_max(ez.xy, mz2));
                ca[i][1] = ca[i][1] +
                    (__builtin_elementwise_min(eZ.zw, mZ2) -
                     __builtin_elementwise_max(ez.zw, mz2));
            }
        }
        #pragma unroll
        for (int i = 0; i < 2; ++i) {   // f32 collapse per chunk
            acc[i][0] += (float)ca[i][0].x;  acc[i][1] += (float)ca[i][0].y;
            acc[i][2] += (float)ca[i][1].x;  acc[i][3] += (float)ca[i][1].y;
        }
    }

    const float cm0 = Cm[m0 + mi], cm1 = Cm[m0 + mi + 1];

    // ---- zero the tile (survivors overwritten by ivr_exact) ----
    #pragma unroll
    for (int i = 0; i < 2; ++i) {
        const int m = m0 + mi + i;
        const int n = n0 + ni;
        if (m < M) {
            if (n + 4 <= N)
                *(float4*)&out[(size_t)m * N + n] = make_float4(0.f, 0.f, 0.f, 0.f);
            else
                for (int j = 0; j < 4; ++j) if (n + j < N) out[(size_t)m * N + n + j] = 0.f;
        }
    }
    // ---- ballot-compact survivors into queue ----
    const int lane = tx & 63;
    #pragma unroll
    for (int i = 0; i < 2; ++i) {
        const int m = m0 + mi + i;
        const float cmv = i ? cm1 : cm0;
        #pragma unroll
        for (int j = 0; j < 4; ++j) {
            const int n = n0 + ni + j;
            const bool flag = (acc[i][j] >= cmv) && (n < N) && (m < M);
            const unsigned long long mask = __ballot(flag);
            if (mask) {
                const int lead = (int)__ffsll(mask) - 1;
                unsigned base = 0;
                if (lane == lead) base = atomicAdd(qcount, (unsigned)__popcll(mask));
                base = (unsigned)__shfl((int)base, lead, 64);
                if (flag) {
                    const unsigned off =
                        (unsigned)__popcll(mask & ((1ull << lane) - 1ull));
                    const unsigned idx = base + off;
                    if (idx < qcap) queue[idx] = ((unsigned)m << 16) | (unsigned)n;
                }
            }
        }
    }
}

// ---------------- kernel 3: exact path on compacted survivors ----------------
__global__ __launch_bounds__(256)
void ivr_exact(const float* __restrict__ men, const float* __restrict__ en,
               float* __restrict__ out, const float* __restrict__ ws,
               int N, unsigned qcap) {
    const unsigned nq0 = *((const unsigned*)ws);
    const unsigned nq = nq0 < qcap ? nq0 : qcap;
    const float* rcM = (const float*)((const char*)ws + 16) + 256;
    const unsigned* queue = (const unsigned*)((const char*)ws + QOFF);
    for (unsigned idx = blockIdx.x * 256 + threadIdx.x; idx < nq;
         idx += gridDim.x * 256) {
        const unsigned id = queue[idx];
        const int m = (int)(id >> 16), n = (int)(id & 0xFFFFu);
        const float* mr = men + (size_t)m * 128;
        const float* er = en + (size_t)n * 128;
        float p = 1.f;
        #pragma unroll 1
        for (int c = 0; c < 8; ++c) {
            float q = 1.f;
            #pragma unroll
            for (int h = 0; h < 2; ++h) {
                const int d0 = c * 8 + h * 4;
                const float4 zm4 = *(const float4*)(mr + d0);
                const float4 Zm4 = *(const float4*)(mr + 64 + d0);
                const float4 ze4 = *(const float4*)(er + d0);
                const float4 Ze4 = *(const float4*)(er + 64 + d0);
                const float zmA[4] = {zm4.x, zm4.y, zm4.z, zm4.w};
                const float ZmA[4] = {Zm4.x, Zm4.y, Zm4.z, Zm4.w};
                const float zeA[4] = {ze4.x, ze4.y, ze4.z, ze4.w};
                const float ZeA[4] = {Ze4.x, Ze4.y, Ze4.z, Ze4.w};
                #pragma unroll
                for (int e = 0; e < 4; ++e) {
                    const float t = fminf(ZmA[e], ZeA[e]) - fmaxf(zmA[e], zeA[e]);
                    const float u = __expf(t);
                    q *= __log2f(1.f + u);
                }
            }
            p *= q * rcM[m * 8 + c];
        }
        out[(size_t)m * N + n] = p;
    }
}

// ---------------- fallback (R2 kernel, self-contained) ----------------
#define FB_MST 34
#define FB_NST 68
__global__ __launch_bounds__(256, 3)
void ivr_fb(const float* __restrict__ men, const float* __restrict__ en,
            float* __restrict__ out, int M, int N) {
    __shared__ __align__(16) float sEm[64][FB_MST];
    __shared__ __align__(16) float sIm[64][FB_MST];
    __shared__ __align__(16) float sEe[64][FB_NST];
    __shared__ __align__(16) float sIe[64][FB_NST];
    __shared__ float sRc[8][FB_MST];
    const int tx = threadIdx.x;
    const int m0 = blockIdx.y * BM;
    const int n0 = blockIdx.x * BN;
    {
        const int m = tx >> 3, c = tx & 7;
        int mm = m0 + m; if (mm >= M) mm = M - 1;
        const float* row = men + (size_t)mm * 128;
        float prod = 1.f;
        #pragma unroll
        for (int k = 0; k < 8; ++k) {
            const int d = c * 8 + k;
            const float Em = __expf(row[64 + d]);
            const float Im = __expf(-row[d]);
            sEm[d][m] = Em; sIm[d][m] = Im;
            prod *= __log2f(fmaf(Em, Im, 1.f));
        }
        sRc[c][m] = 1.f / prod;
    }
    for (int i = tx; i < BN * 64; i += 256) {
        const int d = i & 63, n = i >> 6;
        int nn = n0 + n; if (nn >= N) nn = N - 1;
        sEe[d][n] = __expf(en[(size_t)nn * 128 + 64 + d]);
        sIe[d][n] = __expf(-en[(size_t)nn * 128 + d]);
    }
    __syncthreads();
    const int ni = (tx & 15) * 4, mi = (tx >> 4) * 2;
    float p[2][4];
    #pragma unroll
    for (int i = 0; i < 2; ++i)
        #pragma unroll
        for (int jj = 0; jj < 4; ++jj) p[i][jj] = 1.f;
    #pragma unroll 1
    for (int c = 0; c < 8; ++c) {
        #pragma unroll
        for (int k = 0; k < 8; ++k) {
            const int d = c * 8 + k;
            const float2 Em2 = *(const float2*)&sEm[d][mi];
            const float2 Im2 = *(const float2*)&sIm[d][mi];
            const float2 Ee0 = *(const float2*)&sEe[d][ni];
            const float2 Ee1 = *(const float2*)&sEe[d][ni + 2];
            const float2 Ie0 = *(const float2*)&sIe[d][ni];
            const float2 Ie1 = *(const float2*)&sIe[d][ni + 2];
            const float EmA[2] = {Em2.x, Em2.y}, ImA[2] = {Im2.x, Im2.y};
            const float EeA[4] = {Ee0.x, Ee0.y, Ee1.x, Ee1.y};
            const float IeA[4] = {Ie0.x, Ie0.y, Ie1.x, Ie1.y};
            #pragma unroll
            for (int i = 0; i < 2; ++i)
                #pragma unroll
                for (int jj = 0; jj < 4; ++jj) {
                    const float ww = fmaf(fminf(EmA[i], EeA[jj]),
                                          fminf(ImA[i], IeA[jj]), 1.f);
                    p[i][jj] *= __log2f(ww);
                }
        }
        const float2 rc = *(const float2*)&sRc[c][mi];
        #pragma unroll
        for (int jj = 0; jj < 4; ++jj) { p[0][jj] *= rc.x; p[1][jj] *= rc.y; }
    }
    #pragma unroll
    for (int i = 0; i < 2; ++i) {
        const int m = m0 + mi + i;
        if (m >= M) continue;
        const int n = n0 + ni;
        if (n + 4 <= N) *(float4*)&out[(size_t)m * N + n] =
            make_float4(p[i][0], p[i][1], p[i][2], p[i][3]);
        else for (int jj = 0; jj < 4; ++jj)
            if (n + jj < N) out[(size_t)m * N + n + jj] = p[i][jj];
    }
}

extern "C" void kernel_launch(void* const* d_in, const int* in_sizes, int n_in,
                              void* d_out, int out_size, void* d_ws, size_t ws_size,
                              hipStream_t stream) {
    const float* men = (const float*)d_in[0];
    const float* en  = (const float*)d_in[1];
    float* out = (float*)d_out;
    const int M = in_sizes[0] / 128;          // 256
    const int N = in_sizes[1] / 128;          // 20000
    const int ntl = (N + BN - 1) / BN;        // 313
    const int mtl = (M + BM - 1) / BM;        // 8
    if (M <= 256 && N < 65536 && ws_size >= (size_t)(QOFF + (1u << 20))) {
        const unsigned qcap = (unsigned)((ws_size - QOFF) / 4);
        ivr_stats<<<1, 256, 0, stream>>>(men, (float*)d_ws, M);
        ivr_bound<<<dim3(ntl, mtl), 256, 0, stream>>>(men, en, out, (float*)d_ws,
                                                      M, N, qcap);
        ivr_exact<<<128, 256, 0, stream>>>(men, en, out, (const float*)d_ws,
                                           N, qcap);
    } else {
        ivr_fb<<<dim3(ntl, mtl), 256, 0, stream>>>(men, en, out, M, N);
    }
}